// Round 15
// baseline (113.199 us; speedup 1.0000x reference)
//
#include <hip/hip_runtime.h>

// MultiHeadAttention  B=2, T=2048, D=1024, NH=16, HD=64
// Round 15: r14 uniform-17-iter flash + T4 counted-vmcnt pipeline on a
// 5-slot LDS ring (80KB, 2 blocks/CU). Main loop never drains vmcnt:
// phase1 stages kt+2, waits vmcnt(2) (tile kt+1 forced landed, kt+2 in
// flight); phase2 stages t0+3/t0+4, waits vmcnt(2). One transition drain.
// Semantics identical to r14 (passed). GEMMs unchanged (r8 single-buffer).

typedef __bf16 bf16x8 __attribute__((ext_vector_type(8)));
typedef float f32x4 __attribute__((ext_vector_type(4)));
typedef unsigned short ushortx8 __attribute__((ext_vector_type(8)));
typedef unsigned short ushortx4 __attribute__((ext_vector_type(4)));

#define T_SEQ 2048
#define NHEAD 16
#define HDIM 64
#define DMODEL 1024

__device__ inline unsigned short f2bf(float f) {
  unsigned int u = __builtin_bit_cast(unsigned int, f);
  unsigned int r = (u + 0x7fffu + ((u >> 16) & 1u)) >> 16;
  return (unsigned short)r;
}

__device__ inline void gl16(const unsigned short* g, unsigned short* l) {
  __builtin_amdgcn_global_load_lds(
      (const __attribute__((address_space(1))) unsigned int*)g,
      (__attribute__((address_space(3))) unsigned int*)l, 16, 0, 0);
}

// x (NX elems) then Wq,Wk,Wv,Wo (NXD each) -> contiguous bf16 at out
__global__ void cast_all(const float* __restrict__ x, const float* __restrict__ w0,
                         const float* __restrict__ w1, const float* __restrict__ w2,
                         const float* __restrict__ w3, unsigned short* __restrict__ out) {
  const int NX = 2 * T_SEQ * DMODEL;
  int i = (blockIdx.x * 256 + threadIdx.x) * 4;
  const float* src;
  int off;
  if (i < NX) {
    src = x; off = i;
  } else {
    const int j = i - NX;
    const int sel = j >> 20;
    off = j & ((1 << 20) - 1);
    src = sel == 0 ? w0 : sel == 1 ? w1 : sel == 2 ? w2 : w3;
  }
  float4 v = *reinterpret_cast<const float4*>(src + off);
  ushortx4 o;
  o[0] = f2bf(v.x); o[1] = f2bf(v.y); o[2] = f2bf(v.z); o[3] = f2bf(v.w);
  *reinterpret_cast<ushortx4*>(out + i) = o;
}

// 128x128 bf16 MFMA mainloop — m97 single-buffer (16KB LDS, 2 barriers/iter),
// global_load_lds w16, chunk-XOR swizzle (cancels both sides).
__device__ __forceinline__ void gemm_core(
    const unsigned short* __restrict__ A, const unsigned short* __restrict__ Bw,
    int K, int m0, int n0, f32x4 acc[4][4]) {
  __shared__ unsigned short As[4096];
  __shared__ unsigned short Bs[4096];
  const int tid = threadIdx.x;
  const int lane = tid & 63, wid = tid >> 6;
  const int wr = wid >> 1, wc = wid & 1;
  const int lr = lane & 15, lg = lane >> 4;
  const int srow = tid >> 2;                       // 0..63 (and +64)
  const int scs = ((tid & 3) ^ (srow & 3)) * 8;    // pre-swizzled source chunk
  const unsigned short* ga0 = A + (size_t)(m0 + srow) * K + scs;
  const unsigned short* gb0 = Bw + (size_t)(n0 + srow) * K + scs;
  unsigned short* la0 = As + tid * 8;
  unsigned short* lb0 = Bs + tid * 8;
  const int rca = (lg ^ (lr & 3)) * 8;             // read chunk

  for (int k0 = 0; k0 < K; k0 += 32) {
    __syncthreads();
    gl16(ga0 + k0, la0);
    gl16(ga0 + (size_t)64 * K + k0, la0 + 2048);
    gl16(gb0 + k0, lb0);
    gl16(gb0 + (size_t)64 * K + k0, lb0 + 2048);
    __syncthreads();

    bf16x8 af[4], bfr[4];
#pragma unroll
    for (int t = 0; t < 4; ++t) {
      af[t]  = *reinterpret_cast<const bf16x8*>(&As[(wr * 64 + t * 16 + lr) * 32 + rca]);
      bfr[t] = *reinterpret_cast<const bf16x8*>(&Bs[(wc * 64 + t * 16 + lr) * 32 + rca]);
    }
#pragma unroll
    for (int mi = 0; mi < 4; ++mi)
#pragma unroll
      for (int ni = 0; ni < 4; ++ni)
        acc[mi][ni] = __builtin_amdgcn_mfma_f32_16x16x32_bf16(af[mi], bfr[ni], acc[mi][ni], 0, 0, 0);
  }
}

// Fused Q/K/V projections, grid (256, 3).
__global__ __launch_bounds__(256) void gemm_qkv(
    const unsigned short* __restrict__ xb, const unsigned short* __restrict__ Wall,
    unsigned short* __restrict__ Qb, unsigned short* __restrict__ Kb,
    unsigned short* __restrict__ Vtb) {
  const int z = blockIdx.y;
  const int bid = blockIdx.x;
  int m0, n0;
  const unsigned short* A;
  const unsigned short* Bw;
  if (z < 2) {
    n0 = (bid & 7) * 128; m0 = (bid >> 3) * 128;
    A = xb; Bw = Wall + (size_t)z * (DMODEL * DMODEL);
  } else {
    m0 = (bid & 7) * 128; n0 = (bid >> 3) * 128;
    A = Wall + (size_t)2 * (DMODEL * DMODEL); Bw = xb;
  }
  f32x4 acc[4][4] = {};
  gemm_core(A, Bw, DMODEL, m0, n0, acc);

  const int tid = threadIdx.x, lane = tid & 63, wid = tid >> 6;
  const int wr = wid >> 1, wc = wid & 1, lr = lane & 15, lg = lane >> 4;
  const int mb = m0 + wr * 64, nb = n0 + wc * 64;
  const float scale = z == 0 ? 0.125f * 1.44269504089f : 1.0f;  // exp2 domain
#pragma unroll
  for (int mi = 0; mi < 4; ++mi)
#pragma unroll
    for (int ni = 0; ni < 4; ++ni) {
      const int col = nb + ni * 16 + lr;
#pragma unroll
      for (int j = 0; j < 4; ++j) {
        const int row = mb + mi * 16 + lg * 4 + j;
        const float v = acc[mi][ni][j] * scale;
        if (z < 2) {
          const int b = row >> 11, t = row & (T_SEQ - 1);
          const int h = col >> 6, d = col & (HDIM - 1);
          unsigned short* out = z == 0 ? Qb : Kb;
          out[(((size_t)(b * NHEAD + h) * T_SEQ + t) << 6) + d] = f2bf(v);
        } else {
          const int h = row >> 6, d = row & (HDIM - 1);
          const int b = col >> 11, t = col & (T_SEQ - 1);
          Vtb[(((size_t)(b * NHEAD + h) * HDIM + d) << 11) + t] = f2bf(v);
        }
      }
    }
}

__global__ __launch_bounds__(256) void gemm_proj(
    const unsigned short* __restrict__ Ob, const unsigned short* __restrict__ Wob,
    float* __restrict__ out, const float* __restrict__ bias) {
  const int m0 = blockIdx.y * 128, n0 = blockIdx.x * 128;
  f32x4 acc[4][4] = {};
  gemm_core(Ob, Wob, DMODEL, m0, n0, acc);

  const int tid = threadIdx.x, lane = tid & 63, wid = tid >> 6;
  const int wr = wid >> 1, wc = wid & 1, lr = lane & 15, lg = lane >> 4;
  const int mb = m0 + wr * 64, nb = n0 + wc * 64;
#pragma unroll
  for (int mi = 0; mi < 4; ++mi)
#pragma unroll
    for (int ni = 0; ni < 4; ++ni) {
      const int col = nb + ni * 16 + lr;
      const float bv = bias[col];
#pragma unroll
      for (int j = 0; j < 4; ++j) {
        const int row = mb + mi * 16 + lg * 4 + j;
        out[(size_t)row * DMODEL + col] = acc[mi][ni][j] + bv;
      }
    }
}

// One k-tile attention step (swapped-QK layout, exp2 domain, defer-max).
__device__ __forceinline__ void attn_step(
    const unsigned short* Kslot, const unsigned short* Vslot,
    const int kh0, const int kh1, const int (&vo)[2][2],
    const bf16x8 (&qf)[2], f32x4 (&acc)[4], float& mrun, float& lrun,
    const bool domask, const int kb, const int q, const int lg) {
  f32x4 s[4] = {};
  __builtin_amdgcn_s_setprio(1);
#pragma unroll
  for (int c = 0; c < 4; ++c) {
    bf16x8 k0 = *reinterpret_cast<const bf16x8*>(&Kslot[kh0 + c * 1024]);
    bf16x8 k1 = *reinterpret_cast<const bf16x8*>(&Kslot[kh1 + c * 1024]);
    s[c] = __builtin_amdgcn_mfma_f32_16x16x32_bf16(k0, qf[0], s[c], 0, 0, 0);
    s[c] = __builtin_amdgcn_mfma_f32_16x16x32_bf16(k1, qf[1], s[c], 0, 0, 0);
  }
  __builtin_amdgcn_s_setprio(0);
  if (domask) {
#pragma unroll
    for (int c = 0; c < 4; ++c)
#pragma unroll
      for (int j = 0; j < 4; ++j) {
        const int k = kb + c * 16 + lg * 4 + j;
        if (k > q) s[c][j] = -INFINITY;
      }
  }
  float tm = -INFINITY;
#pragma unroll
  for (int c = 0; c < 4; ++c)
#pragma unroll
    for (int j = 0; j < 4; ++j) tm = fmaxf(tm, s[c][j]);
  tm = fmaxf(tm, __shfl_xor(tm, 16, 64));
  tm = fmaxf(tm, __shfl_xor(tm, 32, 64));
  if (!__all(tm <= mrun + 8.f)) {   // defer-max
    const float mnew = fmaxf(mrun, tm);
    const float fac = exp2f(mrun - mnew);
    lrun *= fac;
#pragma unroll
    for (int dt = 0; dt < 4; ++dt)
#pragma unroll
      for (int j = 0; j < 4; ++j) acc[dt][j] *= fac;  // fac lane-local (col q)
    mrun = mnew;
  }
  float tsum = 0.f;
#pragma unroll
  for (int c = 0; c < 4; ++c)
#pragma unroll
    for (int j = 0; j < 4; ++j) {
      const float p = exp2f(s[c][j] - mrun);  // <= 2^8; exp2(-inf)=0 kills masked
      s[c][j] = p;
      tsum += p;
    }
  tsum += __shfl_xor(tsum, 16, 64);
  tsum += __shfl_xor(tsum, 32, 64);
  lrun += tsum;

  bf16x8 pb[2];
#pragma unroll
  for (int ks = 0; ks < 2; ++ks) {
    bf16x8 t8;
#pragma unroll
    for (int e = 0; e < 8; ++e) t8[e] = (__bf16)s[ks * 2 + (e >> 2)][e & 3];
    pb[ks] = t8;
  }
  __builtin_amdgcn_s_setprio(1);
#pragma unroll
  for (int dt = 0; dt < 4; ++dt) {
#pragma unroll
    for (int ks = 0; ks < 2; ++ks) {
      uint2 vlo = *reinterpret_cast<const uint2*>(&Vslot[vo[ks][0] + dt * 1024]);
      uint2 vhi = *reinterpret_cast<const uint2*>(&Vslot[vo[ks][1] + dt * 1024]);
      uint4 u;
      u.x = vlo.x; u.y = vlo.y; u.z = vhi.x; u.w = vhi.y;
      bf16x8 vf = __builtin_bit_cast(bf16x8, u);
      acc[dt] = __builtin_amdgcn_mfma_f32_16x16x32_bf16(vf, pb[ks], acc[dt], 0, 0, 0);
    }
  }
  __builtin_amdgcn_s_setprio(0);
}

// Flash attention, causal, uniform 17-iter blocks, counted-vmcnt 5-slot ring.
// 8 waves, q-tile pair (a = (bid>>5)&15, b = 31-a). Grid 512 = 2 blocks/CU
// (80KB LDS). Phase1: group0 tile-a rows, group1 tile-b rows, 1 tile/iter,
// stage kt+2, vmcnt(2). Phase2: all on tile-b rows, 2 tiles/iter (group1: t0
// continuing its state, group0: t0+1 fresh partial), stage t0+3/t0+4,
// vmcnt(2). Merge partials at end via LDS.
__global__ __launch_bounds__(512, 4) void flash_attn(
    const unsigned short* __restrict__ Q, const unsigned short* __restrict__ Kg,
    const unsigned short* __restrict__ Vt, unsigned short* __restrict__ O) {
  __shared__ unsigned short Ks[5][4096];  // 5-slot ring, slot = tile % 5
  __shared__ unsigned short Vs[5][4096];
  const int tid = threadIdx.x, lane = tid & 63, wid = tid >> 6;  // wid 0..7
  const int lr = lane & 15, lg = lane >> 4, wq = wid & 3;
  const int bid = blockIdx.x;
  const int bh = (bid & 7) * 4 + ((bid >> 3) & 3);  // XCD-local bh
  const int a = (bid >> 5) & 15;                    // 0..15
  const int b = 31 - a;                             // 16..31
  const bool g0 = wid < 4;
  const int myq1 = g0 ? a : b;
  const int q1 = myq1 * 64 + wq * 16 + lr;          // phase-1 rows (output rows)
  const int q2 = b * 64 + wq * 16 + lr;             // phase-2 rows (tile b)
  const size_t base = (size_t)bh * (T_SEQ * HDIM);

  bf16x8 qf1[2], qf2[2];
#pragma unroll
  for (int h = 0; h < 2; ++h) {
    qf1[h] = *reinterpret_cast<const bf16x8*>(Q + base + (size_t)q1 * HDIM + h * 32 + lg * 8);
    qf2[h] = *reinterpret_cast<const bf16x8*>(Q + base + (size_t)q2 * HDIM + h * 32 + lg * 8);
  }

  // staging: 512 threads cover one 64x64 tile per gl16 (row tid>>3, chunk
  // tid&7), source chunk pre-XORed by row&7 (both-sides swizzle).
  const int srow = tid >> 3;
  const int schk = ((tid & 7) ^ (srow & 7)) * 8;
  const unsigned short* kst = Kg + base + (size_t)srow * HDIM + schk;
  const unsigned short* vst = Vt + base + (size_t)srow * T_SEQ + schk;

#define STAGE(slot, kt_)                                \
  do {                                                  \
    const int kb_ = (kt_) * 64;                         \
    gl16(kst + (size_t)kb_ * HDIM, &Ks[slot][tid * 8]); \
    gl16(vst + kb_, &Vs[slot][tid * 8]);                \
  } while (0)

  // compressed swizzled LDS offsets: full = off + c*1024 (K) / dt*1024 (V)
  const int kh0 = lr * 64 + (((0 * 4 + lg) ^ (lr & 7)) * 8);
  const int kh1 = lr * 64 + (((1 * 4 + lg) ^ (lr & 7)) * 8);
  int vo[2][2];
#pragma unroll
  for (int ks = 0; ks < 2; ++ks) {
    vo[ks][0] = lr * 64 + (((ks * 4 + (lg >> 1)) ^ (lr & 7)) * 8) + (lg & 1) * 4;
    vo[ks][1] = lr * 64 + (((ks * 4 + 2 + (lg >> 1)) ^ (lr & 7)) * 8) + (lg & 1) * 4;
  }

  float m1 = -INFINITY, l1 = 0.f, m2 = -INFINITY, l2 = 0.f;
  f32x4 acc1[4] = {}, acc2[4] = {};

  // ---- prologue: stage tiles 0,1; wait tile0 landed (tile1 in flight ok
  // would race: compute reads tile0 only, but barrier visibility needs the
  // collective wait -> vmcnt(2) forces Q loads + tile0, allows tile1. ----
  STAGE(0, 0);
  STAGE(1, 1);
  asm volatile("s_waitcnt vmcnt(2)" ::: "memory");
  __builtin_amdgcn_s_barrier();
  asm volatile("" ::: "memory");

  int sl = 0;  // slot of current tile
  // ---- Phase 1: kt = 0..a; 1 tile/iter; stage kt+2; vmcnt(2) ----
  for (int kt = 0; kt <= a; ++kt) {
    const int st = kt + 2;
    int sst = sl + 2; if (sst >= 5) sst -= 5;
    if (st <= b) STAGE(sst, st);
    attn_step(Ks[sl], Vs[sl], kh0, kh1, vo, qf1, acc1, m1, l1,
              g0 && (kt == a), kt * 64, q1, lg);
    if (kt < a && st <= b) {
      asm volatile("s_waitcnt vmcnt(2)" ::: "memory");  // kt+1 landed, kt+2 in flight
    } else {
      asm volatile("s_waitcnt vmcnt(0)" ::: "memory");  // transition drain (once)
    }
    __builtin_amdgcn_s_barrier();
    asm volatile("" ::: "memory");
    ++sl; if (sl >= 5) sl -= 5;
  }

  // ---- Phase-2 prologue: stage a+3 (tiles <= a+2 all landed, 0 in flight) ----
  {
    int s3 = sl + 2; if (s3 >= 5) s3 -= 5;  // slot of (a+1)+2
    if (a + 3 <= b) STAGE(s3, a + 3);
  }
  // ---- Phase 2: t0 = a+1..b step 2; 2 tiles/iter; stage t0+3,t0+4; vmcnt(2) ----
  for (int t0 = a + 1; t0 <= b; t0 += 2) {
    int s1 = sl + 1; if (s1 >= 5) s1 -= 5;
    int s3 = sl + 3; if (s3 >= 5) s3 -= 5;
    int s4 = sl + 4; if (s4 >= 5) s4 -= 5;
    if (t0 + 3 <= b) STAGE(s3, t0 + 3);
    if (t0 + 4 <= b) STAGE(s4, t0 + 4);
    if (!g0) {
      attn_step(Ks[sl], Vs[sl], kh0, kh1, vo, qf2, acc1, m1, l1,
                t0 == b, t0 * 64, q2, lg);
    } else if (t0 + 1 <= b) {
      attn_step(Ks[s1], Vs[s1], kh0, kh1, vo, qf2, acc2, m2, l2,
                false, (t0 + 1) * 64, q2, lg);
    }
    if (t0 + 4 <= b) {
      asm volatile("s_waitcnt vmcnt(2)" ::: "memory");  // t0+3 landed, t0+4 in flight
    } else {
      asm volatile("s_waitcnt vmcnt(0)" ::: "memory");  // endgame
    }
    __builtin_amdgcn_s_barrier();
    asm volatile("" ::: "memory");
    sl += 2; if (sl >= 5) sl -= 5;
  }
#undef STAGE

  // ---- Merge group0's phase-2 partial into group1's state (via LDS) ----
  float* sm = reinterpret_cast<float*>(&Ks[0][0]);  // 18KB scratch, all reads done
  const int lid = (wq * 64 + lane) * 18;
  if (g0) {
    float* p = sm + lid;
    p[0] = m2; p[1] = l2;
#pragma unroll
    for (int dt = 0; dt < 4; ++dt)
#pragma unroll
      for (int j = 0; j < 4; ++j) p[2 + dt * 4 + j] = acc2[dt][j];
  }
  __syncthreads();
  if (!g0) {
    const float* p = sm + lid;
    const float mo = p[0], lo = p[1];
    const float ms = fmaxf(m1, mo);
    const float f1 = exp2f(m1 - ms), f2 = exp2f(mo - ms);
    l1 = l1 * f1 + lo * f2;
#pragma unroll
    for (int dt = 0; dt < 4; ++dt)
#pragma unroll
      for (int j = 0; j < 4; ++j)
        acc1[dt][j] = acc1[dt][j] * f1 + p[2 + dt * 4 + j] * f2;
  }

  // ---- epilogue: O[b_, q1, h*64+d]; group0 writes tile a, group1 tile b ----
  const int b_ = bh >> 4, h_ = bh & (NHEAD - 1);
  const float inv = 1.0f / l1;
  unsigned short* orow = O + (((size_t)(b_ * T_SEQ + q1)) << 10) + h_ * HDIM + lg * 4;
#pragma unroll
  for (int dt = 0; dt < 4; ++dt) {
    ushortx4 o4;
#pragma unroll
    for (int j = 0; j < 4; ++j) o4[j] = f2bf(acc1[dt][j] * inv);
    *reinterpret_cast<ushortx4*>(orow + dt * 16) = o4;
  }
}

extern "C" void kernel_launch(void* const* d_in, const int* in_sizes, int n_in,
                              void* d_out, int out_size, void* d_ws, size_t ws_size,
                              hipStream_t stream) {
  const float* x  = (const float*)d_in[0];
  const float* Wq = (const float*)d_in[1];
  const float* Wk = (const float*)d_in[2];
  const float* Wv = (const float*)d_in[3];
  const float* Wo = (const float*)d_in[4];
  const float* bo = (const float*)d_in[5];
  float* out = (float*)d_out;

  const int M = 2 * T_SEQ;          // 4096
  const int NXD = DMODEL * DMODEL;  // 1048576
  const int NX = M * DMODEL;        // 4194304

  unsigned short* ws = (unsigned short*)d_ws;
  unsigned short* xb  = ws;
  unsigned short* Wqb = xb + NX;                 // Wq,Wk,Wv,Wo contiguous
  unsigned short* Wob = Wqb + 3 * (size_t)NXD;
  unsigned short* Qb  = Wqb + 4 * (size_t)NXD;   // [b,h,t,d], pre-scaled 0.125*log2e
  unsigned short* Kbf = Qb + NX;                 // [b,h,t,d]
  unsigned short* Vtb = Kbf + NX;                // [b,h,d,t]
  unsigned short* Ob  = Vtb + NX;                // [b,t,D]

  cast_all<<<(NX + 4 * NXD) / 1024, 256, 0, stream>>>(x, Wq, Wk, Wv, Wo, xb);

  dim3 gq(256, 3);
  gemm_qkv<<<gq, 256, 0, stream>>>(xb, Wqb, Qb, Kbf, Vtb);

  flash_attn<<<512, 512, 0, stream>>>(Qb, Kbf, Vtb, Ob);

  dim3 gg(DMODEL / 128, M / 128);
  gemm_proj<<<gg, 256, 0, stream>>>(Ob, Wob, out, bo);
}

// Round 16
// 104.053 us; speedup vs baseline: 1.0879x; 1.0879x over previous
//
#include <hip/hip_runtime.h>

// MultiHeadAttention  B=2, T=2048, D=1024, NH=16, HD=64
// Round 16: flash VALU-diet — nibble-permuted Vt layout (PV fragment = one
// ds_read_b128 instead of 2x b64 + rebuild), lane-partial lrun (reduce in
// epilogue). proj GEMM -> 128x64 tile (512 blocks = 2/CU). Rest = r15.

typedef __bf16 bf16x8 __attribute__((ext_vector_type(8)));
typedef float f32x4 __attribute__((ext_vector_type(4)));
typedef unsigned short ushortx8 __attribute__((ext_vector_type(8)));
typedef unsigned short ushortx4 __attribute__((ext_vector_type(4)));

#define T_SEQ 2048
#define NHEAD 16
#define HDIM 64
#define DMODEL 1024

__device__ inline unsigned short f2bf(float f) {
  unsigned int u = __builtin_bit_cast(unsigned int, f);
  unsigned int r = (u + 0x7fffu + ((u >> 16) & 1u)) >> 16;
  return (unsigned short)r;
}

__device__ inline void gl16(const unsigned short* g, unsigned short* l) {
  __builtin_amdgcn_global_load_lds(
      (const __attribute__((address_space(1))) unsigned int*)g,
      (__attribute__((address_space(3))) unsigned int*)l, 16, 0, 0);
}

// x (NX elems) then Wq,Wk,Wv,Wo (NXD each) -> contiguous bf16 at out
__global__ void cast_all(const float* __restrict__ x, const float* __restrict__ w0,
                         const float* __restrict__ w1, const float* __restrict__ w2,
                         const float* __restrict__ w3, unsigned short* __restrict__ out) {
  const int NX = 2 * T_SEQ * DMODEL;
  int i = (blockIdx.x * 256 + threadIdx.x) * 4;
  const float* src;
  int off;
  if (i < NX) {
    src = x; off = i;
  } else {
    const int j = i - NX;
    const int sel = j >> 20;
    off = j & ((1 << 20) - 1);
    src = sel == 0 ? w0 : sel == 1 ? w1 : sel == 2 ? w2 : w3;
  }
  float4 v = *reinterpret_cast<const float4*>(src + off);
  ushortx4 o;
  o[0] = f2bf(v.x); o[1] = f2bf(v.y); o[2] = f2bf(v.z); o[3] = f2bf(v.w);
  *reinterpret_cast<ushortx4*>(out + i) = o;
}

// 128x128 bf16 MFMA mainloop — m97 single-buffer (16KB LDS, 2 barriers/iter),
// global_load_lds w16, chunk-XOR swizzle (cancels both sides).
__device__ __forceinline__ void gemm_core(
    const unsigned short* __restrict__ A, const unsigned short* __restrict__ Bw,
    int K, int m0, int n0, f32x4 acc[4][4]) {
  __shared__ unsigned short As[4096];
  __shared__ unsigned short Bs[4096];
  const int tid = threadIdx.x;
  const int lane = tid & 63, wid = tid >> 6;
  const int wr = wid >> 1, wc = wid & 1;
  const int lr = lane & 15, lg = lane >> 4;
  const int srow = tid >> 2;                       // 0..63 (and +64)
  const int scs = ((tid & 3) ^ (srow & 3)) * 8;    // pre-swizzled source chunk
  const unsigned short* ga0 = A + (size_t)(m0 + srow) * K + scs;
  const unsigned short* gb0 = Bw + (size_t)(n0 + srow) * K + scs;
  unsigned short* la0 = As + tid * 8;
  unsigned short* lb0 = Bs + tid * 8;
  const int rca = (lg ^ (lr & 3)) * 8;             // read chunk

  for (int k0 = 0; k0 < K; k0 += 32) {
    __syncthreads();
    gl16(ga0 + k0, la0);
    gl16(ga0 + (size_t)64 * K + k0, la0 + 2048);
    gl16(gb0 + k0, lb0);
    gl16(gb0 + (size_t)64 * K + k0, lb0 + 2048);
    __syncthreads();

    bf16x8 af[4], bfr[4];
#pragma unroll
    for (int t = 0; t < 4; ++t) {
      af[t]  = *reinterpret_cast<const bf16x8*>(&As[(wr * 64 + t * 16 + lr) * 32 + rca]);
      bfr[t] = *reinterpret_cast<const bf16x8*>(&Bs[(wc * 64 + t * 16 + lr) * 32 + rca]);
    }
#pragma unroll
    for (int mi = 0; mi < 4; ++mi)
#pragma unroll
      for (int ni = 0; ni < 4; ++ni)
        acc[mi][ni] = __builtin_amdgcn_mfma_f32_16x16x32_bf16(af[mi], bfr[ni], acc[mi][ni], 0, 0, 0);
  }
}

// 128x64 variant for proj (512 blocks = 2/CU). A 128 rows, B 64 rows, 12KB LDS.
__device__ __forceinline__ void gemm_core_n64(
    const unsigned short* __restrict__ A, const unsigned short* __restrict__ Bw,
    int K, int m0, int n0, f32x4 acc[4][2]) {
  __shared__ unsigned short As[4096];   // 128 x 32
  __shared__ unsigned short Bs[2048];   // 64 x 32
  const int tid = threadIdx.x;
  const int lane = tid & 63, wid = tid >> 6;
  const int wr = wid >> 1, wc = wid & 1;
  const int lr = lane & 15, lg = lane >> 4;
  const int srow = tid >> 2;
  const int scs = ((tid & 3) ^ (srow & 3)) * 8;
  const unsigned short* ga0 = A + (size_t)(m0 + srow) * K + scs;
  const unsigned short* gb0 = Bw + (size_t)(n0 + srow) * K + scs;
  unsigned short* la0 = As + tid * 8;
  unsigned short* lb0 = Bs + tid * 8;
  const int rca = (lg ^ (lr & 3)) * 8;

  for (int k0 = 0; k0 < K; k0 += 32) {
    __syncthreads();
    gl16(ga0 + k0, la0);
    gl16(ga0 + (size_t)64 * K + k0, la0 + 2048);
    gl16(gb0 + k0, lb0);
    __syncthreads();

    bf16x8 af[4], bfr[2];
#pragma unroll
    for (int t = 0; t < 4; ++t)
      af[t] = *reinterpret_cast<const bf16x8*>(&As[(wr * 64 + t * 16 + lr) * 32 + rca]);
#pragma unroll
    for (int t = 0; t < 2; ++t)
      bfr[t] = *reinterpret_cast<const bf16x8*>(&Bs[(wc * 32 + t * 16 + lr) * 32 + rca]);
#pragma unroll
    for (int mi = 0; mi < 4; ++mi)
#pragma unroll
      for (int ni = 0; ni < 2; ++ni)
        acc[mi][ni] = __builtin_amdgcn_mfma_f32_16x16x32_bf16(af[mi], bfr[ni], acc[mi][ni], 0, 0, 0);
  }
}

// Fused Q/K/V projections, grid (256, 3).
// z=0: Q = x@Wq^T scaled -> [b,h,t,d]; z=1: K -> [b,h,t,d];
// z=2: V^T = Wv@x^T -> [b,h,d,t'] with t nibble-permuted within 64-blocks
// (nib' = ((nib&3)<<1)|(nib>>2) per 32-half) so flash PV frags are contiguous.
__global__ __launch_bounds__(256) void gemm_qkv(
    const unsigned short* __restrict__ xb, const unsigned short* __restrict__ Wall,
    unsigned short* __restrict__ Qb, unsigned short* __restrict__ Kb,
    unsigned short* __restrict__ Vtb) {
  const int z = blockIdx.y;
  const int bid = blockIdx.x;
  int m0, n0;
  const unsigned short* A;
  const unsigned short* Bw;
  if (z < 2) {
    n0 = (bid & 7) * 128; m0 = (bid >> 3) * 128;
    A = xb; Bw = Wall + (size_t)z * (DMODEL * DMODEL);
  } else {
    m0 = (bid & 7) * 128; n0 = (bid >> 3) * 128;
    A = Wall + (size_t)2 * (DMODEL * DMODEL); Bw = xb;
  }
  f32x4 acc[4][4] = {};
  gemm_core(A, Bw, DMODEL, m0, n0, acc);

  const int tid = threadIdx.x, lane = tid & 63, wid = tid >> 6;
  const int wr = wid >> 1, wc = wid & 1, lr = lane & 15, lg = lane >> 4;
  const int mb = m0 + wr * 64, nb = n0 + wc * 64;
  const float scale = z == 0 ? 0.125f * 1.44269504089f : 1.0f;  // exp2 domain
#pragma unroll
  for (int mi = 0; mi < 4; ++mi)
#pragma unroll
    for (int ni = 0; ni < 4; ++ni) {
      const int col = nb + ni * 16 + lr;
#pragma unroll
      for (int j = 0; j < 4; ++j) {
        const int row = mb + mi * 16 + lg * 4 + j;
        const float v = acc[mi][ni][j] * scale;
        if (z < 2) {
          const int b = row >> 11, t = row & (T_SEQ - 1);
          const int h = col >> 6, d = col & (HDIM - 1);
          unsigned short* out = z == 0 ? Qb : Kb;
          out[(((size_t)(b * NHEAD + h) * T_SEQ + t) << 6) + d] = f2bf(v);
        } else {
          const int h = row >> 6, d = row & (HDIM - 1);
          const int b = col >> 11, tt = col & (T_SEQ - 1);
          const int nib = (tt >> 2) & 7;
          const int nib2 = ((nib & 3) << 1) | (nib >> 2);
          const int tp = (tt & ~31) | (nib2 << 2) | (tt & 3);
          Vtb[(((size_t)(b * NHEAD + h) * HDIM + d) << 11) + tp] = f2bf(v);
        }
      }
    }
}

__global__ __launch_bounds__(256) void gemm_proj(
    const unsigned short* __restrict__ Ob, const unsigned short* __restrict__ Wob,
    float* __restrict__ out, const float* __restrict__ bias) {
  const int m0 = blockIdx.y * 128, n0 = blockIdx.x * 64;
  f32x4 acc[4][2] = {};
  gemm_core_n64(Ob, Wob, DMODEL, m0, n0, acc);

  const int tid = threadIdx.x, lane = tid & 63, wid = tid >> 6;
  const int wr = wid >> 1, wc = wid & 1, lr = lane & 15, lg = lane >> 4;
  const int mb = m0 + wr * 64, nb = n0 + wc * 32;
#pragma unroll
  for (int mi = 0; mi < 4; ++mi)
#pragma unroll
    for (int ni = 0; ni < 2; ++ni) {
      const int col = nb + ni * 16 + lr;
      const float bv = bias[col];
#pragma unroll
      for (int j = 0; j < 4; ++j) {
        const int row = mb + mi * 16 + lg * 4 + j;
        out[(size_t)row * DMODEL + col] = acc[mi][ni][j] + bv;
      }
    }
}

// One k-tile attention step (swapped-QK layout, exp2 domain, defer-max,
// lane-partial lrun). V frag = one ds_read_b128 (nibble-permuted Vt).
__device__ __forceinline__ void attn_step(
    const unsigned short* Kslot, const unsigned short* Vslot,
    const int kh0, const int kh1, const int (&vo)[2],
    const bf16x8 (&qf)[2], f32x4 (&acc)[4], float& mrun, float& lrun,
    const bool domask, const int kb, const int q, const int lg) {
  f32x4 s[4] = {};
  __builtin_amdgcn_s_setprio(1);
#pragma unroll
  for (int c = 0; c < 4; ++c) {
    bf16x8 k0 = *reinterpret_cast<const bf16x8*>(&Kslot[kh0 + c * 1024]);
    bf16x8 k1 = *reinterpret_cast<const bf16x8*>(&Kslot[kh1 + c * 1024]);
    s[c] = __builtin_amdgcn_mfma_f32_16x16x32_bf16(k0, qf[0], s[c], 0, 0, 0);
    s[c] = __builtin_amdgcn_mfma_f32_16x16x32_bf16(k1, qf[1], s[c], 0, 0, 0);
  }
  __builtin_amdgcn_s_setprio(0);
  if (domask) {
#pragma unroll
    for (int c = 0; c < 4; ++c)
#pragma unroll
      for (int j = 0; j < 4; ++j) {
        const int k = kb + c * 16 + lg * 4 + j;
        if (k > q) s[c][j] = -INFINITY;
      }
  }
  float tm = -INFINITY;
#pragma unroll
  for (int c = 0; c < 4; ++c)
#pragma unroll
    for (int j = 0; j < 4; ++j) tm = fmaxf(tm, s[c][j]);
  tm = fmaxf(tm, __shfl_xor(tm, 16, 64));
  tm = fmaxf(tm, __shfl_xor(tm, 32, 64));
  if (!__all(tm <= mrun + 8.f)) {   // defer-max
    const float mnew = fmaxf(mrun, tm);
    const float fac = exp2f(mrun - mnew);
    lrun *= fac;                    // lane-partial, row-uniform fac
#pragma unroll
    for (int dt = 0; dt < 4; ++dt)
#pragma unroll
      for (int j = 0; j < 4; ++j) acc[dt][j] *= fac;  // fac lane-local (col q)
    mrun = mnew;
  }
  float tsum = 0.f;
#pragma unroll
  for (int c = 0; c < 4; ++c)
#pragma unroll
    for (int j = 0; j < 4; ++j) {
      const float p = exp2f(s[c][j] - mrun);  // <= 2^8; exp2(-inf)=0 kills masked
      s[c][j] = p;
      tsum += p;
    }
  lrun += tsum;  // lane-partial; reduced in epilogue

  bf16x8 pb[2];
#pragma unroll
  for (int ks = 0; ks < 2; ++ks) {
    bf16x8 t8;
#pragma unroll
    for (int e = 0; e < 8; ++e) t8[e] = (__bf16)s[ks * 2 + (e >> 2)][e & 3];
    pb[ks] = t8;
  }
  __builtin_amdgcn_s_setprio(1);
#pragma unroll
  for (int dt = 0; dt < 4; ++dt) {
#pragma unroll
    for (int ks = 0; ks < 2; ++ks) {
      bf16x8 vf = *reinterpret_cast<const bf16x8*>(&Vslot[vo[ks] + dt * 1024]);
      acc[dt] = __builtin_amdgcn_mfma_f32_16x16x32_bf16(vf, pb[ks], acc[dt], 0, 0, 0);
    }
  }
  __builtin_amdgcn_s_setprio(0);
}

// Flash attention, causal, uniform 17-iter blocks, counted-vmcnt 5-slot ring.
// 8 waves, q-tile pair (a = (bid>>5)&15, b = 31-a). Grid 512 = 2 blocks/CU.
__global__ __launch_bounds__(512, 4) void flash_attn(
    const unsigned short* __restrict__ Q, const unsigned short* __restrict__ Kg,
    const unsigned short* __restrict__ Vt, unsigned short* __restrict__ O) {
  __shared__ unsigned short Ks[5][4096];  // 5-slot ring, slot = tile % 5
  __shared__ unsigned short Vs[5][4096];
  const int tid = threadIdx.x, lane = tid & 63, wid = tid >> 6;  // wid 0..7
  const int lr = lane & 15, lg = lane >> 4, wq = wid & 3;
  const int bid = blockIdx.x;
  const int bh = (bid & 7) * 4 + ((bid >> 3) & 3);  // XCD-local bh
  const int a = (bid >> 5) & 15;                    // 0..15
  const int b = 31 - a;                             // 16..31
  const bool g0 = wid < 4;
  const int myq1 = g0 ? a : b;
  const int q1 = myq1 * 64 + wq * 16 + lr;          // phase-1 rows (output rows)
  const int q2 = b * 64 + wq * 16 + lr;             // phase-2 rows (tile b)
  const size_t base = (size_t)bh * (T_SEQ * HDIM);

  bf16x8 qf1[2], qf2[2];
#pragma unroll
  for (int h = 0; h < 2; ++h) {
    qf1[h] = *reinterpret_cast<const bf16x8*>(Q + base + (size_t)q1 * HDIM + h * 32 + lg * 8);
    qf2[h] = *reinterpret_cast<const bf16x8*>(Q + base + (size_t)q2 * HDIM + h * 32 + lg * 8);
  }

  // staging: 512 threads cover one 64x64 tile per gl16 (row tid>>3, chunk
  // tid&7), source chunk pre-XORed by row&7 (both-sides swizzle).
  const int srow = tid >> 3;
  const int schk = ((tid & 7) ^ (srow & 7)) * 8;
  const unsigned short* kst = Kg + base + (size_t)srow * HDIM + schk;
  const unsigned short* vst = Vt + base + (size_t)srow * T_SEQ + schk;

#define STAGE(slot, kt_)                                \
  do {                                                  \
    const int kb_ = (kt_) * 64;                         \
    gl16(kst + (size_t)kb_ * HDIM, &Ks[slot][tid * 8]); \
    gl16(vst + kb_, &Vs[slot][tid * 8]);                \
  } while (0)

  // swizzled LDS offsets: K frag halves; V frag = one b128 per (ks) (+dt*1024)
  const int kh0 = lr * 64 + ((lg ^ (lr & 7)) * 8);
  const int kh1 = lr * 64 + (((4 + lg) ^ (lr & 7)) * 8);
  int vo[2];
#pragma unroll
  for (int ks = 0; ks < 2; ++ks)
    vo[ks] = lr * 64 + (((ks * 4 + lg) ^ (lr & 7)) * 8);

  float m1 = -INFINITY, l1 = 0.f, m2 = -INFINITY, l2 = 0.f;
  f32x4 acc1[4] = {}, acc2[4] = {};

  STAGE(0, 0);
  STAGE(1, 1);
  asm volatile("s_waitcnt vmcnt(2)" ::: "memory");  // tile0 + Q landed, tile1 in flight
  __builtin_amdgcn_s_barrier();
  asm volatile("" ::: "memory");

  int sl = 0;  // slot of current tile
  // ---- Phase 1: kt = 0..a; 1 tile/iter; stage kt+2; vmcnt(2) ----
  for (int kt = 0; kt <= a; ++kt) {
    const int st = kt + 2;
    int sst = sl + 2; if (sst >= 5) sst -= 5;
    if (st <= b) STAGE(sst, st);
    attn_step(Ks[sl], Vs[sl], kh0, kh1, vo, qf1, acc1, m1, l1,
              g0 && (kt == a), kt * 64, q1, lg);
    if (kt < a && st <= b) {
      asm volatile("s_waitcnt vmcnt(2)" ::: "memory");  // kt+1 landed, kt+2 in flight
    } else {
      asm volatile("s_waitcnt vmcnt(0)" ::: "memory");  // transition drain (once)
    }
    __builtin_amdgcn_s_barrier();
    asm volatile("" ::: "memory");
    ++sl; if (sl >= 5) sl -= 5;
  }

  // ---- Phase-2 prologue: stage a+3 (tiles <= a+2 all landed, 0 in flight) ----
  {
    int s3 = sl + 2; if (s3 >= 5) s3 -= 5;  // slot of (a+1)+2
    if (a + 3 <= b) STAGE(s3, a + 3);
  }
  // ---- Phase 2: t0 = a+1..b step 2; 2 tiles/iter; stage t0+3,t0+4; vmcnt(2) ----
  for (int t0 = a + 1; t0 <= b; t0 += 2) {
    int s1 = sl + 1; if (s1 >= 5) s1 -= 5;
    int s3 = sl + 3; if (s3 >= 5) s3 -= 5;
    int s4 = sl + 4; if (s4 >= 5) s4 -= 5;
    if (t0 + 3 <= b) STAGE(s3, t0 + 3);
    if (t0 + 4 <= b) STAGE(s4, t0 + 4);
    if (!g0) {
      attn_step(Ks[sl], Vs[sl], kh0, kh1, vo, qf2, acc1, m1, l1,
                t0 == b, t0 * 64, q2, lg);
    } else if (t0 + 1 <= b) {
      attn_step(Ks[s1], Vs[s1], kh0, kh1, vo, qf2, acc2, m2, l2,
                false, (t0 + 1) * 64, q2, lg);
    }
    if (t0 + 4 <= b) {
      asm volatile("s_waitcnt vmcnt(2)" ::: "memory");  // t0+3 landed, t0+4 in flight
    } else {
      asm volatile("s_waitcnt vmcnt(0)" ::: "memory");  // endgame
    }
    __builtin_amdgcn_s_barrier();
    asm volatile("" ::: "memory");
    sl += 2; if (sl >= 5) sl -= 5;
  }
#undef STAGE

  // ---- Merge group0's phase-2 partial into group1's state (via LDS) ----
  float* sm = reinterpret_cast<float*>(&Ks[0][0]);  // 18KB scratch, all reads done
  const int lid = (wq * 64 + lane) * 18;
  if (g0) {
    float* p = sm + lid;
    p[0] = m2; p[1] = l2;
#pragma unroll
    for (int dt = 0; dt < 4; ++dt)
#pragma unroll
      for (int j = 0; j < 4; ++j) p[2 + dt * 4 + j] = acc2[dt][j];
  }
  __syncthreads();
  if (!g0) {
    const float* p = sm + lid;
    const float mo = p[0], lo = p[1];
    const float ms = fmaxf(m1, mo);
    const float f1 = exp2f(m1 - ms), f2 = exp2f(mo - ms);
    l1 = l1 * f1 + lo * f2;
#pragma unroll
    for (int dt = 0; dt < 4; ++dt)
#pragma unroll
      for (int j = 0; j < 4; ++j)
        acc1[dt][j] = acc1[dt][j] * f1 + p[2 + dt * 4 + j] * f2;
  }

  // ---- reduce lane-partial l1 across the 4 lg groups (once) ----
  l1 += __shfl_xor(l1, 16, 64);
  l1 += __shfl_xor(l1, 32, 64);

  // ---- epilogue: O[b_, q1, h*64+d]; group0 writes tile a, group1 tile b ----
  const int b_ = bh >> 4, h_ = bh & (NHEAD - 1);
  const float inv = 1.0f / l1;
  unsigned short* orow = O + (((size_t)(b_ * T_SEQ + q1)) << 10) + h_ * HDIM + lg * 4;
#pragma unroll
  for (int dt = 0; dt < 4; ++dt) {
    ushortx4 o4;
#pragma unroll
    for (int j = 0; j < 4; ++j) o4[j] = f2bf(acc1[dt][j] * inv);
    *reinterpret_cast<ushortx4*>(orow + dt * 16) = o4;
  }
}

extern "C" void kernel_launch(void* const* d_in, const int* in_sizes, int n_in,
                              void* d_out, int out_size, void* d_ws, size_t ws_size,
                              hipStream_t stream) {
  const float* x  = (const float*)d_in[0];
  const float* Wq = (const float*)d_in[1];
  const float* Wk = (const float*)d_in[2];
  const float* Wv = (const float*)d_in[3];
  const float* Wo = (const float*)d_in[4];
  const float* bo = (const float*)d_in[5];
  float* out = (float*)d_out;

  const int M = 2 * T_SEQ;          // 4096
  const int NXD = DMODEL * DMODEL;  // 1048576
  const int NX = M * DMODEL;        // 4194304

  unsigned short* ws = (unsigned short*)d_ws;
  unsigned short* xb  = ws;
  unsigned short* Wqb = xb + NX;                 // Wq,Wk,Wv,Wo contiguous
  unsigned short* Wob = Wqb + 3 * (size_t)NXD;
  unsigned short* Qb  = Wqb + 4 * (size_t)NXD;   // [b,h,t,d], pre-scaled 0.125*log2e
  unsigned short* Kbf = Qb + NX;                 // [b,h,t,d]
  unsigned short* Vtb = Kbf + NX;                // [b,h,d,t'] nibble-permuted
  unsigned short* Ob  = Vtb + NX;                // [b,t,D]

  cast_all<<<(NX + 4 * NXD) / 1024, 256, 0, stream>>>(x, Wq, Wk, Wv, Wo, xb);

  dim3 gq(256, 3);
  gemm_qkv<<<gq, 256, 0, stream>>>(xb, Wqb, Qb, Kbf, Vtb);

  flash_attn<<<512, 512, 0, stream>>>(Qb, Kbf, Vtb, Ob);

  dim3 gg(DMODEL / 64, M / 128);  // (16, 32) = 512 blocks
  gemm_proj<<<gg, 256, 0, stream>>>(Ob, Wob, out, bo);
}